// Round 6
// baseline (676.280 us; speedup 1.0000x reference)
//
#include <hip/hip_runtime.h>

#define SEQ 720
#define DIM 2048
#define NH 16
#define HD 128
#define CACHE 11520
#define KSP 12
#define KCH (CACHE / KSP)      // 960
#define KTILES (KCH / 32)      // 30
#define LOG2E 1.4426950408889634f
#define SM_SCALE 0.08838834764831845f  // 1/sqrt(128)
#define CSCL (SM_SCALE * LOG2E)

typedef unsigned short u16;
typedef unsigned int u32;
typedef __bf16 bf8_t __attribute__((ext_vector_type(8)));
typedef float f4 __attribute__((ext_vector_type(4)));

static_assert(KCH * KSP == CACHE && KTILES * 32 == KCH, "split");

__device__ __forceinline__ float bf2f(u16 v) {
    union { u32 u; float f; } t; t.u = ((u32)v) << 16; return t.f;
}
__device__ __forceinline__ u16 f2bf(float f) {
    union { float f; u32 u; } t; t.f = f;
    u32 u = t.u;
    return (u16)((u + 0x7fffu + ((u >> 16) & 1u)) >> 16);
}
// hardware bf16 convert (RTNE) — saves 3 VALU ops vs f2bf in hot loops
__device__ __forceinline__ u16 f2bf_hw(float f) {
    __bf16 b = (__bf16)f;
    u16 u; __builtin_memcpy(&u, &b, 2); return u;
}
__device__ __forceinline__ bf8_t ld_bf8(const u16* p) {
    const u16* pa = (const u16*)__builtin_assume_aligned(p, 16);
    bf8_t r;
    __builtin_memcpy(&r, pa, 16);
    return r;
}
__device__ __forceinline__ uint4 ld_u4g(const u16* p) {
    uint4 r;
    __builtin_memcpy(&r, (const u16*)__builtin_assume_aligned(p, 16), 16);
    return r;
}
__device__ __forceinline__ void st_u4l(u16* p, uint4 v) {
    __builtin_memcpy((u16*)__builtin_assume_aligned(p, 16), &v, 16);
}
__device__ __forceinline__ void st8(u16* p, const u16* v) {
    __builtin_memcpy((u16*)__builtin_assume_aligned(p, 16), v, 16);
}
__device__ __forceinline__ void ld8_cvt(const void* base, size_t off, int f32, u16* dst) {
    if (f32) {
        const float* p = (const float*)base + off;
        float v[8];
        __builtin_memcpy(v, (const float*)__builtin_assume_aligned(p, 16), 32);
        #pragma unroll
        for (int i = 0; i < 8; i++) dst[i] = f2bf(v[i]);
    } else {
        const u16* p = (const u16*)base + off;
        __builtin_memcpy(dst, (const u16*)__builtin_assume_aligned(p, 16), 16);
    }
}
__device__ __forceinline__ float ld1(const void* base, size_t off, int f32) {
    return f32 ? ((const float*)base)[off] : bf2f(((const u16*)base)[off]);
}
__device__ __forceinline__ int ls_from(const int* cs_p, const int* sink_p) {
    const int cs = cs_p[0], sink = sink_p[0];
    const int rolling = CACHE - sink;
    int ls = (cs - sink) % rolling + sink;
    if (ls > CACHE - SEQ) ls = CACHE - SEQ;
    return ls;
}

// ---------------------------------------------------------------------------
// Dtype probe (proven rounds 3-5)
// ---------------------------------------------------------------------------
__global__ __launch_bounds__(256) void detect_kernel(const void* probe, int* flag) {
    __shared__ int cnt[256];
    const int tid = threadIdx.x;
    const u16* p = (const u16*)probe;
    int bad = 0;
    for (int i = tid; i < 4096; i += 256) {
        int e = (p[i] >> 7) & 0xFF;
        bad += (e < 0x60 || e > 0x90) ? 1 : 0;
    }
    cnt[tid] = bad;
    __syncthreads();
    if (tid == 0) {
        int s = 0;
        for (int i = 0; i < 256; i++) s += cnt[i];
        flag[0] = (s > 256) ? 1 : 0;
    }
}

__global__ __launch_bounds__(256) void zero_kernel(float* p, int n) {
    int i = blockIdx.x * 256 + threadIdx.x;
    if (i < n) p[i] = 0.f;
}

// cvt4: up to 4 fp32(or bf16)->bf16 streams via grid.y
__global__ __launch_bounds__(256) void cvt4_kernel(
    const void* __restrict__ s0, const void* __restrict__ s1,
    const void* __restrict__ s2, const void* __restrict__ s3,
    u16* __restrict__ d0, u16* __restrict__ d1,
    u16* __restrict__ d2, u16* __restrict__ d3,
    int n, const int* __restrict__ dflag)
{
    const int f32 = dflag[0];
    const int z = blockIdx.y;
    const void* s = (z == 0) ? s0 : (z == 1) ? s1 : (z == 2) ? s2 : s3;
    u16* d = (z == 0) ? d0 : (z == 1) ? d1 : (z == 2) ? d2 : d3;
    const int idx = (blockIdx.x * 256 + threadIdx.x) * 8;
    if (idx < n) {
        u16 t[8];
        ld8_cvt(s, idx, f32, t);
        st8(d + idx, t);
    }
}

// ---------------------------------------------------------------------------
// GEMM3: C[M x 2048] = A[M x 2048] * W^T + bias, bf16 inputs.
// BM=128, BN=64, BK=64; 4 waves x (64x32 = 4x2 frags). XOR-swizzled LDS.
// Register prefetch: kb+1 global loads issued before the MFMA block.
// ---------------------------------------------------------------------------
__device__ __forceinline__ void gemm3_body(const u16* __restrict__ A,
                                           const u16* __restrict__ W,
                                           const u16* __restrict__ bias,
                                           void* __restrict__ C, int cF32, int M)
{
    __shared__ __align__(16) u16 As[128 * 64];   // 16 KB
    __shared__ __align__(16) u16 Bs[64 * 64];    //  8 KB
    const int tid = threadIdx.x;
    const int wv = tid >> 6, lane = tid & 63, quad = lane >> 4, l16 = lane & 15;
    const int n0 = blockIdx.x * 64, m0 = blockIdx.y * 128;
    const int wr = (wv & 1) * 64, wc = (wv >> 1) * 32;

    f4 acc[4][2];
    #pragma unroll
    for (int i = 0; i < 4; i++) { acc[i][0] = f4{0,0,0,0}; acc[i][1] = f4{0,0,0,0}; }

    const int srow = tid >> 3, scb = tid & 7;   // 32 rows x 8 chunks per pass

    uint4 av[4], bv[2];
    #pragma unroll
    for (int i = 0; i < 4; i++) {
        int gm = m0 + srow + 32 * i; if (gm >= M) gm = M - 1;
        av[i] = ld_u4g(A + (size_t)gm * DIM + scb * 8);
    }
    #pragma unroll
    for (int i = 0; i < 2; i++)
        bv[i] = ld_u4g(W + (size_t)(n0 + srow + 32 * i) * DIM + scb * 8);

    for (int kb = 0; kb < DIM / 64; kb++) {
        __syncthreads();
        #pragma unroll
        for (int i = 0; i < 4; i++) {
            const int row = srow + 32 * i;
            st_u4l(&As[row * 64 + ((scb ^ (row & 7)) * 8)], av[i]);
        }
        #pragma unroll
        for (int i = 0; i < 2; i++) {
            const int row = srow + 32 * i;
            st_u4l(&Bs[row * 64 + ((scb ^ (row & 7)) * 8)], bv[i]);
        }
        __syncthreads();
        if (kb + 1 < DIM / 64) {       // prefetch next K-slab during MFMA
            const int k0 = (kb + 1) * 64;
            #pragma unroll
            for (int i = 0; i < 4; i++) {
                int gm = m0 + srow + 32 * i; if (gm >= M) gm = M - 1;
                av[i] = ld_u4g(A + (size_t)gm * DIM + k0 + scb * 8);
            }
            #pragma unroll
            for (int i = 0; i < 2; i++)
                bv[i] = ld_u4g(W + (size_t)(n0 + srow + 32 * i) * DIM + k0 + scb * 8);
        }
        #pragma unroll
        for (int s = 0; s < 2; s++) {
            bf8_t af[4], bfr[2];
            #pragma unroll
            for (int i = 0; i < 4; i++) {
                const int m = wr + i * 16 + l16;
                af[i] = ld_bf8(&As[m * 64 + (((s * 4 + quad) ^ (m & 7)) * 8)]);
            }
            #pragma unroll
            for (int j = 0; j < 2; j++) {
                const int n = wc + j * 16 + l16;
                bfr[j] = ld_bf8(&Bs[n * 64 + (((s * 4 + quad) ^ (n & 7)) * 8)]);
            }
            #pragma unroll
            for (int mi = 0; mi < 4; mi++)
                #pragma unroll
                for (int nj = 0; nj < 2; nj++)
                    acc[mi][nj] = __builtin_amdgcn_mfma_f32_16x16x32_bf16(af[mi], bfr[nj], acc[mi][nj], 0, 0, 0);
        }
    }

    #pragma unroll
    for (int mi = 0; mi < 4; mi++) {
        const int rowb = m0 + wr + mi * 16 + quad * 4;
        #pragma unroll
        for (int r = 0; r < 4; r++) {
            if (rowb + r < M) {
                #pragma unroll
                for (int nj = 0; nj < 2; nj++) {
                    const int col = n0 + wc + nj * 16 + l16;
                    float v = acc[mi][nj][r] + bf2f(bias[col]);
                    if (cF32) ((float*)C)[(size_t)(rowb + r) * DIM + col] = v;
                    else      ((u16*)C)[(size_t)(rowb + r) * DIM + col] = f2bf(v);
                }
            }
        }
    }
}

__global__ __launch_bounds__(256) void gemm3_qkv_kernel(
    const u16* __restrict__ X,
    const u16* __restrict__ w0, const u16* __restrict__ w1, const u16* __restrict__ w2,
    const u16* __restrict__ b0, const u16* __restrict__ b1, const u16* __restrict__ b2,
    u16* __restrict__ o0, u16* __restrict__ o1, u16* __restrict__ o2, int M)
{
    const int z = blockIdx.z;
    const u16* W = (z == 0) ? w0 : (z == 1) ? w1 : w2;
    const u16* B = (z == 0) ? b0 : (z == 1) ? b1 : b2;
    u16* O = (z == 0) ? o0 : (z == 1) ? o1 : o2;
    gemm3_body(X, W, B, O, 0, M);
}

__global__ __launch_bounds__(256) void gemm3_o_kernel(
    const u16* __restrict__ X, const u16* __restrict__ W,
    const u16* __restrict__ B, void* __restrict__ O,
    const int* __restrict__ dflag, int M)
{
    gemm3_body(X, W, B, O, dflag[0], M);
}

// ---------------------------------------------------------------------------
// RMSNorm + RoPE, in place (proven)
// ---------------------------------------------------------------------------
__global__ __launch_bounds__(256) void normrope_kernel(
    u16* __restrict__ qbuf, u16* __restrict__ kbuf,
    const void* __restrict__ nqw, const void* __restrict__ nkw,
    const void* __restrict__ fcos, const void* __restrict__ fsin,
    const int* __restrict__ dflag)
{
    const int f32 = dflag[0];
    const int row = blockIdx.x, z = blockIdx.y;
    const int tid = threadIdx.x, lane = tid & 63, wvi = tid >> 6;
    u16* buf = ((z == 0) ? qbuf : kbuf) + (size_t)row * DIM + tid * 8;
    u16 in[8];
    __builtin_memcpy(in, (const u16*)__builtin_assume_aligned(buf, 16), 16);
    float x[8];
    #pragma unroll
    for (int i = 0; i < 8; i++) x[i] = bf2f(in[i]);
    float ss = 0.f;
    #pragma unroll
    for (int i = 0; i < 8; i++) ss += x[i] * x[i];
    ss += __shfl_xor(ss, 32); ss += __shfl_xor(ss, 16); ss += __shfl_xor(ss, 8);
    ss += __shfl_xor(ss, 4);  ss += __shfl_xor(ss, 2);  ss += __shfl_xor(ss, 1);
    __shared__ float red[4];
    if (lane == 0) red[wvi] = ss;
    __syncthreads();
    const float rinv = rsqrtf((red[0] + red[1] + red[2] + red[3]) * (1.0f / DIM) + 1e-6f);
    const void* wn = (z == 0) ? nqw : nkw;
    float y[8];
    #pragma unroll
    for (int i = 0; i < 8; i++) y[i] = x[i] * rinv * ld1(wn, tid * 8 + i, f32);
    const int dd = (tid * 8) & (HD - 1);
    const int cb = row * 64 + (dd >> 1);
    u16 outv[8];
    #pragma unroll
    for (int p = 0; p < 4; p++) {
        float cv = ld1(fcos, cb + p, f32), sv = ld1(fsin, cb + p, f32);
        float xr = y[2 * p], xi = y[2 * p + 1];
        outv[2 * p]     = f2bf(xr * cv - xi * sv);
        outv[2 * p + 1] = f2bf(xr * sv + xi * cv);
    }
    __builtin_memcpy((u16*)__builtin_assume_aligned(buf, 16), outv, 16);
}

// ---------------------------------------------------------------------------
// KV pre-pass (proven): Kb[h][key][d] bf16; Vt[h][d][key] bf16 transposed.
// ---------------------------------------------------------------------------
__global__ __launch_bounds__(256) void cvtk_kernel(
    const void* __restrict__ cache_k, const u16* __restrict__ kr,
    u16* __restrict__ Kb, const int* __restrict__ cs_p,
    const int* __restrict__ sink_p, const int* __restrict__ dflag)
{
    const int f32 = dflag[0];
    const int kt = blockIdx.x, h = blockIdx.y, tid = threadIdx.x;
    const int ls = ls_from(cs_p, sink_p);
    #pragma unroll
    for (int i = 0; i < 8; i++) {
        const int idx = i * 2048 + tid * 8;
        const int key = kt * 128 + (idx >> 7);
        const int d0 = idx & 127;
        u16 tmp[8];
        if (key >= ls && key < ls + SEQ)
            ld8_cvt(kr, (size_t)(key - ls) * DIM + h * HD + d0, 0, tmp);
        else
            ld8_cvt(cache_k, (size_t)key * DIM + h * HD + d0, f32, tmp);
        st8(&Kb[((size_t)h * CACHE + key) * HD + d0], tmp);
    }
}

__device__ __forceinline__ int swz(int ky, int cb) {
    return (cb ^ (ky >> 3) ^ ((ky & 7) << 1)) & 15;
}

__global__ __launch_bounds__(256) void cvtv_kernel(
    const void* __restrict__ cache_v, const u16* __restrict__ vr,
    u16* __restrict__ Vt, const int* __restrict__ cs_p,
    const int* __restrict__ sink_p, const int* __restrict__ dflag)
{
    __shared__ __align__(16) u16 Vtile[128 * 128];
    const int f32 = dflag[0];
    const int kt = blockIdx.x, h = blockIdx.y, tid = threadIdx.x;
    const int ls = ls_from(cs_p, sink_p);
    #pragma unroll
    for (int i = 0; i < 8; i++) {
        const int idx = i * 2048 + tid * 8;
        const int ky = idx >> 7;
        const int d0 = idx & 127;
        const int key = kt * 128 + ky;
        u16 tmp[8];
        if (key >= ls && key < ls + SEQ)
            ld8_cvt(vr, (size_t)(key - ls) * DIM + h * HD + d0, 0, tmp);
        else
            ld8_cvt(cache_v, (size_t)key * DIM + h * HD + d0, f32, tmp);
        st8(&Vtile[ky * 128 + swz(ky, d0 >> 3) * 8], tmp);
    }
    __syncthreads();
    #pragma unroll
    for (int i = 0; i < 8; i++) {
        const int oidx = i * 2048 + tid * 8;
        const int d = oidx >> 7;
        const int k8 = oidx & 127;
        u16 o[8];
        #pragma unroll
        for (int j = 0; j < 8; j++) {
            const int ky = k8 + j;
            o[j] = Vtile[ky * 128 + swz(ky, d >> 3) * 8 + (d & 7)];
        }
        st8(&Vt[((size_t)h * HD + d) * CACHE + kt * 128 + k8], o);
    }
}

// ---------------------------------------------------------------------------
// Pipelined barrier-free flash attention. grid (kc=12, qb=6, h=16) = 1152
// blocks (~4.5/CU => up to 18 waves/CU). K reg-prefetch; V hoisted; static-
// max softmax; hw bf16 cvt; partial O stored bf16 (error ~5e-5, see journal).
// ---------------------------------------------------------------------------
__global__ __launch_bounds__(256) void attn3_kernel(
    const u16* __restrict__ qr, const u16* __restrict__ Kb, const u16* __restrict__ Vt,
    u16* __restrict__ pO, float* __restrict__ pL)
{
    __shared__ __align__(16) u16 Ps[4][32 * 40];
    const int tid = threadIdx.x;
    const int wvi = tid >> 6, lane = tid & 63, quad = lane >> 4, l16 = lane & 15;
    const int kc = blockIdx.x, qb = blockIdx.y, h = blockIdx.z;
    const int q0 = qb * 128 + wvi * 32;

    bf8_t aQ[2][4];
    #pragma unroll
    for (int mi = 0; mi < 2; mi++) {
        int qrow = q0 + mi * 16 + l16; if (qrow >= SEQ) qrow = SEQ - 1;
        const u16* qp = qr + (size_t)qrow * DIM + h * HD + quad * 8;
        #pragma unroll
        for (int dc = 0; dc < 4; dc++) aQ[mi][dc] = ld_bf8(qp + dc * 32);
    }

    f4 O[2][8];
    float lsum[2][4];
    #pragma unroll
    for (int mi = 0; mi < 2; mi++) {
        #pragma unroll
        for (int dc = 0; dc < 8; dc++) O[mi][dc] = f4{0.f, 0.f, 0.f, 0.f};
        #pragma unroll
        for (int r = 0; r < 4; r++) lsum[mi][r] = 0.f;
    }

    const u16* kbase = Kb + ((size_t)h * CACHE + (size_t)kc * KCH) * HD;
    const u16* vbase = Vt + (size_t)h * HD * CACHE + (size_t)kc * KCH;

    bf8_t kf[8];
    {
        const u16* kp = kbase + quad * 8;
        #pragma unroll
        for (int dc = 0; dc < 4; dc++) {
            kf[dc]     = ld_bf8(kp + (size_t)l16 * HD + dc * 32);
            kf[4 + dc] = ld_bf8(kp + (size_t)(16 + l16) * HD + dc * 32);
        }
    }

    for (int t = 0; t < KTILES; t++) {
        bf8_t kn[8];
        {
            const int tn = (t + 1 < KTILES) ? t + 1 : t;
            const u16* kp = kbase + (size_t)tn * 32 * HD + quad * 8;
            #pragma unroll
            for (int dc = 0; dc < 4; dc++) {
                kn[dc]     = ld_bf8(kp + (size_t)l16 * HD + dc * 32);
                kn[4 + dc] = ld_bf8(kp + (size_t)(16 + l16) * HD + dc * 32);
            }
        }
        bf8_t vf[8];
        {
            const u16* vp = vbase + t * 32 + quad * 8;
            #pragma unroll
            for (int dc = 0; dc < 8; dc++)
                vf[dc] = ld_bf8(vp + (size_t)(dc * 16 + l16) * CACHE);
        }
        f4 sc[2][2];
        #pragma unroll
        for (int mi = 0; mi < 2; mi++) { sc[mi][0] = f4{0,0,0,0}; sc[mi][1] = f4{0,0,0,0}; }
        #pragma unroll
        for (int dc = 0; dc < 4; dc++) {
            #pragma unroll
            for (int mi = 0; mi < 2; mi++) {
                sc[mi][0] = __builtin_amdgcn_mfma_f32_16x16x32_bf16(aQ[mi][dc], kf[dc],     sc[mi][0], 0, 0, 0);
                sc[mi][1] = __builtin_amdgcn_mfma_f32_16x16x32_bf16(aQ[mi][dc], kf[4 + dc], sc[mi][1], 0, 0, 0);
            }
        }
        #pragma unroll
        for (int mi = 0; mi < 2; mi++) {
            #pragma unroll
            for (int r = 0; r < 4; r++) {
                float p0 = exp2f(sc[mi][0][r] * CSCL);
                float p1 = exp2f(sc[mi][1][r] * CSCL);
                lsum[mi][r] += p0 + p1;
                const int prow = mi * 16 + quad * 4 + r;
                Ps[wvi][prow * 40 + l16]      = f2bf_hw(p0);
                Ps[wvi][prow * 40 + 16 + l16] = f2bf_hw(p1);
            }
        }
        bf8_t ap0 = ld_bf8(&Ps[wvi][l16 * 40 + quad * 8]);
        bf8_t ap1 = ld_bf8(&Ps[wvi][(16 + l16) * 40 + quad * 8]);
        #pragma unroll
        for (int dc = 0; dc < 8; dc++) {
            O[0][dc] = __builtin_amdgcn_mfma_f32_16x16x32_bf16(ap0, vf[dc], O[0][dc], 0, 0, 0);
            O[1][dc] = __builtin_amdgcn_mfma_f32_16x16x32_bf16(ap1, vf[dc], O[1][dc], 0, 0, 0);
        }
        #pragma unroll
        for (int i = 0; i < 8; i++) kf[i] = kn[i];
    }

    #pragma unroll
    for (int mi = 0; mi < 2; mi++)
        #pragma unroll
        for (int r = 0; r < 4; r++) {
            float s = lsum[mi][r];
            s += __shfl_xor(s, 1); s += __shfl_xor(s, 2);
            s += __shfl_xor(s, 4); s += __shfl_xor(s, 8);
            lsum[mi][r] = s;
        }
    #pragma unroll
    for (int mi = 0; mi < 2; mi++) {
        #pragma unroll
        for (int r = 0; r < 4; r++) {
            const int q = q0 + mi * 16 + quad * 4 + r;
            if (q < SEQ) {
                const size_t rb = (size_t)(h * SEQ + q);
                const size_t pb = (rb * KSP + kc) * HD;
                #pragma unroll
                for (int dc = 0; dc < 8; dc++)
                    pO[pb + dc * 16 + l16] = f2bf_hw(O[mi][dc][r]);
                if (l16 == 0) atomicAdd(&pL[rb], lsum[mi][r]);
            }
        }
    }
}

__global__ __launch_bounds__(128) void combine3_kernel(
    const u16* __restrict__ pO, const float* __restrict__ pL,
    u16* __restrict__ attn)
{
    const int q = blockIdx.x, h = blockIdx.y, d = threadIdx.x;
    const size_t rb = (size_t)(h * SEQ + q);
    float num = 0.f;
    #pragma unroll
    for (int s = 0; s < KSP; s++)
        num += bf2f(pO[(rb * KSP + s) * HD + d]);
    attn[(size_t)q * DIM + h * HD + d] = f2bf(num / pL[rb]);
}

// ---------------------------------------------------------------------------
extern "C" void kernel_launch(void* const* d_in, const int* in_sizes, int n_in,
                              void* d_out, int out_size, void* d_ws, size_t ws_size,
                              hipStream_t stream)
{
    const void* x    = d_in[0];
    const void* q_w  = d_in[1];
    const void* q_b  = d_in[2];
    const void* k_w  = d_in[3];
    const void* k_b  = d_in[4];
    const void* v_w  = d_in[5];
    const void* v_b  = d_in[6];
    const void* o_w  = d_in[7];
    const void* o_b  = d_in[8];
    const void* nqw  = d_in[9];
    const void* nkw  = d_in[10];
    const void* cK   = d_in[11];
    const void* cV   = d_in[12];
    const void* fcos = d_in[13];
    const void* fsin = d_in[14];
    const int* cs_p   = (const int*)d_in[15];
    const int* sink_p = (const int*)d_in[17];

    char* ws = (char*)d_ws;
    const size_t SZB  = (size_t)SEQ * DIM * 2;        //  2,949,120
    const size_t KBsz = (size_t)NH * CACHE * HD * 2;  // 47,185,920
    const size_t POsz = (size_t)NH * SEQ * KSP * HD * 2;  // 35,389,440 (bf16)
    const size_t PLsz = (size_t)NH * SEQ * 4;         //     46,080
    const size_t Wsz  = (size_t)DIM * DIM * 2;        //  8,388,608

    int*  dflag = (int*)ws;
    u16*  q_l   = (u16*)(ws + 256);
    u16*  k_l   = (u16*)(ws + 256 + SZB);
    u16*  v_l   = (u16*)(ws + 256 + 2 * SZB);
    u16*  attn  = (u16*)(ws + 256 + 3 * SZB);
    char* pbase = ws + 256 + 4 * SZB;
    u16*   Kb = (u16*)pbase;
    u16*   Vt = (u16*)(pbase + KBsz);
    u16*   pO = (u16*)(pbase + 2 * KBsz);
    float* pL = (float*)(pbase + 2 * KBsz + POsz);
    u16*   Wo = (u16*)(pbase + 2 * KBsz + POsz + PLsz);   // persistent (phase 3)
    u16*   bo = Wo + (size_t)DIM * DIM;
    // total: 256 + 4*SZB + 2*KBsz + POsz + PLsz + Wsz + 4KB ≈ 150.0 MB
    // (<= 153.7 MB proven available in round 4)

    // phase-1 aliases inside the pO region (consumed before attn3 writes pO):
    u16* Wq = pO;
    u16* Wk = Wq + (size_t)DIM * DIM;
    u16* Wv = Wk + (size_t)DIM * DIM;
    u16* x_bf = Wv + (size_t)DIM * DIM;           // 25.2+2.95 < 35.4 MB ✓
    u16* bq = x_bf + (size_t)SEQ * DIM;
    u16* bk = bq + DIM;
    u16* bv = bk + DIM;

    dim3 blk(256);
    detect_kernel<<<1, blk, 0, stream>>>(q_w, dflag);

    // phase 1: conversions + QKV projection + norm/rope
    cvt4_kernel<<<dim3(DIM * DIM / 2048, 4), blk, 0, stream>>>(
        q_w, k_w, v_w, o_w, Wq, Wk, Wv, Wo, DIM * DIM, dflag);
    cvt4_kernel<<<dim3(SEQ * DIM / 2048, 1), blk, 0, stream>>>(
        x, x, x, x, x_bf, x_bf, x_bf, x_bf, SEQ * DIM, dflag);
    cvt4_kernel<<<dim3(1, 4), blk, 0, stream>>>(
        q_b, k_b, v_b, o_b, bq, bk, bv, bo, DIM, dflag);
    gemm3_qkv_kernel<<<dim3(DIM / 64, 6, 3), blk, 0, stream>>>(
        x_bf, Wq, Wk, Wv, bq, bk, bv, q_l, k_l, v_l, SEQ);
    normrope_kernel<<<dim3(SEQ, 2), blk, 0, stream>>>(
        q_l, k_l, nqw, nkw, fcos, fsin, dflag);

    // phase 2: KV merge/convert/transpose + attention + combine
    cvtk_kernel<<<dim3(CACHE / 128, NH), blk, 0, stream>>>(cK, k_l, Kb, cs_p, sink_p, dflag);
    cvtv_kernel<<<dim3(CACHE / 128, NH), blk, 0, stream>>>(cV, v_l, Vt, cs_p, sink_p, dflag);
    {
        int nL = NH * SEQ;
        zero_kernel<<<(nL + 255) / 256, blk, 0, stream>>>(pL, nL);
    }
    attn3_kernel<<<dim3(KSP, 6, NH), blk, 0, stream>>>(q_l, Kb, Vt, pO, pL);
    combine3_kernel<<<dim3(SEQ, NH), dim3(128), 0, stream>>>(pO, pL, attn);

    // phase 3: output projection
    gemm3_o_kernel<<<dim3(DIM / 64, 6), blk, 0, stream>>>(
        attn, Wo, bo, d_out, dflag, SEQ);
}